// Round 1
// baseline (882.903 us; speedup 1.0000x reference)
//
#include <hip/hip_runtime.h>
#include <hip/hip_bf16.h>
#include <math.h>

#define BN_EPS 1e-5f

// ---------------- BatchNorm ----------------
__global__ void bn_stats(const float* __restrict__ x, float* __restrict__ colsum,
                         float* __restrict__ colsq, int N){
  int c = threadIdx.x; // 128 threads
  int rpb = (N + gridDim.x - 1) / gridDim.x;
  int r0 = blockIdx.x * rpb;
  int r1 = r0 + rpb; if (r1 > N) r1 = N;
  float s = 0.f, q = 0.f;
  for (int r = r0; r < r1; ++r){
    float v = x[(size_t)r*128 + c];
    s += v; q += v*v;
  }
  atomicAdd(&colsum[c], s);
  atomicAdd(&colsq[c], q);
}

__global__ void bn_finalize(const float* colsum, const float* colsq, const float* gamma,
                            const float* beta, float* scale, float* shift, int N){
  int c = threadIdx.x;
  float mu  = colsum[c] / (float)N;
  float var = colsq[c] / (float)N - mu*mu;
  float sc  = gamma[c] * rsqrtf(var + BN_EPS);
  scale[c] = sc;
  shift[c] = beta[c] - mu*sc;
}

__global__ void bn_apply(const float* __restrict__ x, const float* __restrict__ scale,
                         const float* __restrict__ shift, float* __restrict__ h, int total4){
  const float4* x4 = (const float4*)x;
  const float4* sc4 = (const float4*)scale;
  const float4* sh4 = (const float4*)shift;
  float4* h4 = (float4*)h;
  for (int idx = blockIdx.x*blockDim.x + threadIdx.x; idx < total4; idx += gridDim.x*blockDim.x){
    int c4 = idx & 31;
    float4 v = x4[idx], sc = sc4[c4], sh = sh4[c4];
    float4 o;
    o.x = v.x*sc.x + sh.x; o.y = v.y*sc.y + sh.y;
    o.z = v.z*sc.z + sh.z; o.w = v.w*sc.w + sh.w;
    h4[idx] = o;
  }
}

// ---------------- CSR build ----------------
__global__ void count_deg(const int* __restrict__ dst, int* __restrict__ indeg, int E){
  int e = blockIdx.x*blockDim.x + threadIdx.x;
  if (e < E) atomicAdd(&indeg[dst[e]], 1);
}

__global__ void dinv_k(const int* __restrict__ indeg, float* __restrict__ dinv, int N){
  int v = blockIdx.x*blockDim.x + threadIdx.x;
  if (v < N) dinv[v] = rsqrtf((float)indeg[v] + 1.0f);  // +1 self loop
}

__global__ void scan_deg(const int* __restrict__ indeg, int* __restrict__ rowstart,
                         int* __restrict__ cursor, int N){
  __shared__ int sh[1024];
  int tid = threadIdx.x;
  int per = (N + 1023) >> 10;
  int a = tid*per, b = a+per; if (b > N) b = N;
  int s = 0;
  if (a < N) for (int i=a;i<b;i++) s += indeg[i];
  sh[tid] = s; __syncthreads();
  for (int d = 1; d < 1024; d <<= 1){
    int t = (tid >= d) ? sh[tid-d] : 0;
    __syncthreads();
    sh[tid] += t;
    __syncthreads();
  }
  int off = sh[tid] - s; // exclusive
  if (a < N) for (int i=a;i<b;i++){ rowstart[i]=off; cursor[i]=off; off += indeg[i]; }
  if (tid == 1023) rowstart[N] = off;
}

__global__ void fill_csr(const int* __restrict__ src, const int* __restrict__ dst,
                         const float* __restrict__ dinv, int* __restrict__ cursor,
                         int* __restrict__ csrs, float* __restrict__ csrn, int E){
  int e = blockIdx.x*blockDim.x + threadIdx.x;
  if (e < E){
    int s = src[e], d = dst[e];
    int pos = atomicAdd(&cursor[d], 1);
    csrs[pos] = s;
    csrn[pos] = dinv[s]*dinv[d];
  }
}

__global__ void gbounds(const int* __restrict__ batch, int* __restrict__ gstart, int N, int G){
  int g = blockIdx.x*blockDim.x + threadIdx.x;
  if (g > G) return;
  int lo = 0, hi = N;
  while (lo < hi){ int mid = (lo+hi)>>1; if (batch[mid] < g) lo = mid+1; else hi = mid; }
  gstart[g] = lo;
}

__global__ void transpose_w(const float* __restrict__ W0, const float* __restrict__ W1,
                            const float* __restrict__ W2, float* __restrict__ Wt){
  int idx = blockIdx.x*blockDim.x + threadIdx.x;
  if (idx >= 3*16384) return;
  int l = idx >> 14, r = idx & 16383, c = r >> 7, k = r & 127;
  const float* W = (l==0) ? W0 : (l==1) ? W1 : W2;
  Wt[idx] = W[k*128 + c];
}

// ---------------- GEMM: C[N,128] = A[N,128] @ W  (Bt = W^T, [col][k]) ----------------
__device__ __forceinline__ int swz64(int i, int k4){
  return i*64 + (((k4 + (i>>3)) & 15) << 2);
}

__global__ __launch_bounds__(256) void gemm128(const float* __restrict__ A, const float* __restrict__ Bt,
                                               float* __restrict__ C, int N){
  __shared__ float As[8192];  // 128 rows x 64 k (swizzled), 32 KB
  __shared__ float Bs[8192];  // 128 cols x 64 k (swizzled), 32 KB
  int tid = threadIdx.x;
  int r0 = blockIdx.x * 128;
  int tx = tid & 15, ty = tid >> 4;
  float acc[8][8];
  #pragma unroll
  for (int r=0;r<8;r++)
    #pragma unroll
    for (int c=0;c<8;c++) acc[r][c] = 0.f;

  for (int st = 0; st < 2; ++st){
    if (st) __syncthreads();
    for (int it = 0; it < 8; ++it){
      int idx = tid + it*256;       // 0..2047
      int i = idx >> 4, k4 = idx & 15;
      int r = r0 + i;
      float4 av = (r < N) ? *(const float4*)(A + (size_t)r*128 + st*64 + k4*4)
                          : make_float4(0.f,0.f,0.f,0.f);
      *(float4*)(As + swz64(i,k4)) = av;
      float4 bv = *(const float4*)(Bt + (size_t)i*128 + st*64 + k4*4);
      *(float4*)(Bs + swz64(i,k4)) = bv;
    }
    __syncthreads();
    for (int k4 = 0; k4 < 16; ++k4){
      float4 a[8], b[8];
      #pragma unroll
      for (int r=0;r<8;r++) a[r] = *(const float4*)(As + swz64(ty*8+r, k4));
      #pragma unroll
      for (int c=0;c<8;c++) b[c] = *(const float4*)(Bs + swz64(tx*8+c, k4));
      #pragma unroll
      for (int r=0;r<8;r++)
        #pragma unroll
        for (int c=0;c<8;c++)
          acc[r][c] += a[r].x*b[c].x + a[r].y*b[c].y + a[r].z*b[c].z + a[r].w*b[c].w;
    }
  }

  #pragma unroll
  for (int r=0;r<8;r++){
    int rr = r0 + ty*8 + r;
    if (rr < N){
      float4 o0 = make_float4(acc[r][0], acc[r][1], acc[r][2], acc[r][3]);
      float4 o1 = make_float4(acc[r][4], acc[r][5], acc[r][6], acc[r][7]);
      *(float4*)(C + (size_t)rr*128 + tx*8)     = o0;
      *(float4*)(C + (size_t)rr*128 + tx*8 + 4) = o1;
    }
  }
}

// ---------------- fused aggregation + bias + squash + attention ----------------
__global__ __launch_bounds__(256) void gather_squash(
    const float* __restrict__ m, const int* __restrict__ rowstart,
    const int* __restrict__ csrs, const float* __restrict__ csrn,
    const float* __restrict__ dinv, const float* __restrict__ bias,
    const float* __restrict__ tar, float* __restrict__ h, float* __restrict__ attn, int N){
  int node = blockIdx.x*4 + (threadIdx.x >> 6);
  if (node >= N) return;
  int lane = threadIdx.x & 63;
  float dv = dinv[node];
  float sn = dv*dv;   // self-loop norm = 1/deg
  float2 v = ((const float2*)(m + (size_t)node*128))[lane];
  float a0 = v.x*sn, a1 = v.y*sn;
  int j0 = rowstart[node], j1 = rowstart[node+1];
  for (int j = j0; j < j1; ++j){
    int s = csrs[j];
    float w = csrn[j];
    float2 mv = ((const float2*)(m + (size_t)s*128))[lane];
    a0 += w*mv.x; a1 += w*mv.y;
  }
  float2 bv = ((const float2*)bias)[lane];
  a0 += bv.x; a1 += bv.y;
  float n2 = a0*a0 + a1*a1;
  #pragma unroll
  for (int o = 32; o > 0; o >>= 1) n2 += __shfl_xor(n2, o);
  float sc = (n2/(1.f+n2)) * rsqrtf(n2 + 1e-12f);
  float h0 = a0*sc, h1 = a1*sc;
  ((float2*)(h + (size_t)node*128))[lane] = make_float2(h0, h1);
  float2 tv = ((const float2*)tar)[lane];
  float at = h0*tv.x + h1*tv.y;
  #pragma unroll
  for (int o = 32; o > 0; o >>= 1) at += __shfl_xor(at, o);
  if (lane == 0) attn[node] = at;
}

// ---------------- per-graph readout (wsum / mean / max), accumulated ----------------
__global__ __launch_bounds__(1024) void readout(const float* __restrict__ h,
                                                const float* __restrict__ attn,
                                                const int* __restrict__ gstart,
                                                float* __restrict__ grep){
  int g = blockIdx.x;
  int t   = threadIdx.x & 127;  // feature
  int grp = threadIdx.x >> 7;   // 0..7 node groups
  int a = gstart[g], b = gstart[g+1];
  float ws = 0.f, sm = 0.f, mx = -INFINITY;
  for (int n = a + grp; n < b; n += 8){
    float v  = h[(size_t)n*128 + t];
    float at = attn[n];
    ws += at*v; sm += v; mx = fmaxf(mx, v);
  }
  __shared__ float sws[8][128], ssm[8][128], smx[8][128];
  sws[grp][t] = ws; ssm[grp][t] = sm; smx[grp][t] = mx;
  __syncthreads();
  if (grp == 0){
    #pragma unroll
    for (int j = 1; j < 8; ++j){
      ws += sws[j][t]; sm += ssm[j][t]; mx = fmaxf(mx, smx[j][t]);
    }
    int cnt = b - a;
    float mean = sm / fmaxf((float)cnt, 1.f);
    if (cnt == 0) mx = 0.f;
    grep[(size_t)g*384 + t]       += ws;
    grep[(size_t)g*384 + 128 + t] += mean;
    grep[(size_t)g*384 + 256 + t] += mx;
  }
}

// ---------------- classifier head + log_softmax ----------------
__global__ __launch_bounds__(128) void classify(const float* __restrict__ grep,
                                                const float* __restrict__ w1, const float* __restrict__ b1,
                                                const float* __restrict__ w2, const float* __restrict__ b2,
                                                float* __restrict__ out){
  int g = blockIdx.x, t = threadIdx.x;
  __shared__ float gr[384];
  for (int i = t; i < 384; i += 128) gr[i] = grep[(size_t)g*384 + i];
  __syncthreads();
  float z = b1[t];
  for (int k = 0; k < 384; ++k) z += gr[k]*w1[k*128 + t];
  z = fmaxf(z, 0.f);
  float c0 = z*w2[t*2 + 0], c1 = z*w2[t*2 + 1];
  #pragma unroll
  for (int o = 32; o > 0; o >>= 1){ c0 += __shfl_xor(c0, o); c1 += __shfl_xor(c1, o); }
  __shared__ float r0s[2], r1s[2];
  if ((t & 63) == 0){ r0s[t>>6] = c0; r1s[t>>6] = c1; }
  __syncthreads();
  if (t == 0){
    float z0 = r0s[0] + r1s[0]*0.f + r0s[1] + b2[0];   // careful: fixed below
    // (recompute cleanly)
    z0 = r0s[0] + r0s[1] + b2[0];
    float z1 = r1s[0] + r1s[1] + b2[1];
    float mm = fmaxf(z0, z1);
    float lse = mm + logf(expf(z0-mm) + expf(z1-mm));
    out[g*2 + 0] = z0 - lse;
    out[g*2 + 1] = z1 - lse;
  }
}

extern "C" void kernel_launch(void* const* d_in, const int* in_sizes, int n_in,
                              void* d_out, int out_size, void* d_ws, size_t ws_size,
                              hipStream_t stream) {
  const float* x     = (const float*)d_in[0];
  const int*   ei    = (const int*)d_in[1];
  const int*   batch = (const int*)d_in[2];
  const float* gamma = (const float*)d_in[3];
  const float* beta  = (const float*)d_in[4];
  const float* W0    = (const float*)d_in[5];
  const float* b0    = (const float*)d_in[6];
  const float* W1    = (const float*)d_in[7];
  const float* b1    = (const float*)d_in[8];
  const float* W2    = (const float*)d_in[9];
  const float* b2    = (const float*)d_in[10];
  const float* tar   = (const float*)d_in[11];
  const float* l1w   = (const float*)d_in[12];
  const float* l1b   = (const float*)d_in[13];
  const float* l2w   = (const float*)d_in[14];
  const float* l2b   = (const float*)d_in[15];
  float* out = (float*)d_out;

  int N = in_sizes[0] / 128;
  int E = in_sizes[1] / 2;
  int G = out_size / 2;
  const int* srcp = ei;
  const int* dstp = ei + E;

  char* wsb = (char*)d_ws;
  size_t off = 0;
  auto alloc = [&](size_t bytes)->char*{
    char* p = wsb + off; off += (bytes + 255) & ~(size_t)255; return p;
  };
  float* h       = (float*)alloc((size_t)N*128*4);
  float* m       = (float*)alloc((size_t)N*128*4);
  float* attn    = (float*)alloc((size_t)N*4);
  float* dinv    = (float*)alloc((size_t)N*4);
  int*   indeg   = (int*)  alloc((size_t)N*4);
  int*   rowst   = (int*)  alloc((size_t)(N+1)*4);
  int*   cursor  = (int*)  alloc((size_t)N*4);
  int*   csrs    = (int*)  alloc((size_t)E*4);
  float* csrn    = (float*)alloc((size_t)E*4);
  int*   gstart  = (int*)  alloc((size_t)(G+1)*4);
  float* grep    = (float*)alloc((size_t)G*384*4);
  float* stats   = (float*)alloc(4*128*4);
  float* Wt      = (float*)alloc(3*16384*4);
  (void)ws_size;

  float* colsum = stats;
  float* colsq  = stats + 128;
  float* scale  = stats + 256;
  float* shift  = stats + 384;

  hipMemsetAsync(colsum, 0, 2*128*4, stream);
  hipMemsetAsync(indeg, 0, (size_t)N*4, stream);
  hipMemsetAsync(grep, 0, (size_t)G*384*4, stream);

  bn_stats<<<512, 128, 0, stream>>>(x, colsum, colsq, N);
  bn_finalize<<<1, 128, 0, stream>>>(colsum, colsq, gamma, beta, scale, shift, N);
  bn_apply<<<2048, 256, 0, stream>>>(x, scale, shift, h, N*32);

  count_deg<<<(E+255)/256, 256, 0, stream>>>(dstp, indeg, E);
  dinv_k<<<(N+255)/256, 256, 0, stream>>>(indeg, dinv, N);
  scan_deg<<<1, 1024, 0, stream>>>(indeg, rowst, cursor, N);
  fill_csr<<<(E+255)/256, 256, 0, stream>>>(srcp, dstp, dinv, cursor, csrs, csrn, E);
  gbounds<<<(G+1+255)/256, 256, 0, stream>>>(batch, gstart, N, G);
  transpose_w<<<(3*16384+255)/256, 256, 0, stream>>>(W0, W1, W2, Wt);

  const float* bs[3] = {b0, b1, b2};
  for (int l = 0; l < 3; ++l){
    gemm128<<<(N+127)/128, 256, 0, stream>>>(h, Wt + l*16384, m, N);
    gather_squash<<<(N+3)/4, 256, 0, stream>>>(m, rowst, csrs, csrn, dinv, bs[l], tar + l*128, h, attn, N);
    readout<<<G, 1024, 0, stream>>>(h, attn, gstart, grep);
  }
  classify<<<G, 128, 0, stream>>>(grep, l1w, l1b, l2w, l2b, out);
}

// Round 2
// 669.184 us; speedup vs baseline: 1.3194x; 1.3194x over previous
//
#include <hip/hip_runtime.h>
#include <hip/hip_bf16.h>
#include <math.h>

#define BN_EPS 1e-5f
#define SCAN_CHUNK 1024

// ---------------- BatchNorm ----------------
__global__ void bn_stats(const float* __restrict__ x, float* __restrict__ colsum,
                         float* __restrict__ colsq, int N){
  int c = threadIdx.x; // 128 threads
  int rpb = (N + gridDim.x - 1) / gridDim.x;
  int r0 = blockIdx.x * rpb;
  int r1 = r0 + rpb; if (r1 > N) r1 = N;
  float s = 0.f, q = 0.f;
  for (int r = r0; r < r1; ++r){
    float v = x[(size_t)r*128 + c];
    s += v; q += v*v;
  }
  atomicAdd(&colsum[c], s);
  atomicAdd(&colsq[c], q);
}

__global__ void bn_finalize(const float* colsum, const float* colsq, const float* gamma,
                            const float* beta, float* scale, float* shift, int N){
  int c = threadIdx.x;
  float mu  = colsum[c] / (float)N;
  float var = colsq[c] / (float)N - mu*mu;
  float sc  = gamma[c] * rsqrtf(var + BN_EPS);
  scale[c] = sc;
  shift[c] = beta[c] - mu*sc;
}

__global__ void bn_apply(const float* __restrict__ x, const float* __restrict__ scale,
                         const float* __restrict__ shift, float* __restrict__ h, int total4){
  const float4* x4 = (const float4*)x;
  const float4* sc4 = (const float4*)scale;
  const float4* sh4 = (const float4*)shift;
  float4* h4 = (float4*)h;
  for (int idx = blockIdx.x*blockDim.x + threadIdx.x; idx < total4; idx += gridDim.x*blockDim.x){
    int c4 = idx & 31;
    float4 v = x4[idx], sc = sc4[c4], sh = sh4[c4];
    float4 o;
    o.x = v.x*sc.x + sh.x; o.y = v.y*sc.y + sh.y;
    o.z = v.z*sc.z + sh.z; o.w = v.w*sc.w + sh.w;
    h4[idx] = o;
  }
}

// ---------------- CSR build ----------------
__global__ void count_deg(const int* __restrict__ dst, int* __restrict__ indeg, int E){
  int e = blockIdx.x*blockDim.x + threadIdx.x;
  if (e < E) atomicAdd(&indeg[dst[e]], 1);
}

__global__ void dinv_k(const int* __restrict__ indeg, float* __restrict__ dinv, int N){
  int v = blockIdx.x*blockDim.x + threadIdx.x;
  if (v < N) dinv[v] = rsqrtf((float)indeg[v] + 1.0f);  // +1 self loop
}

// ---- hierarchical exclusive scan of indeg -> rowstart, cursor ----
__global__ __launch_bounds__(256) void scan_part(const int* __restrict__ indeg,
                                                 int* __restrict__ bsum, int N){
  __shared__ int sh[256];
  int base = blockIdx.x * SCAN_CHUNK;
  int s = 0;
  for (int i = threadIdx.x; i < SCAN_CHUNK; i += 256){
    int idx = base + i;
    if (idx < N) s += indeg[idx];
  }
  sh[threadIdx.x] = s; __syncthreads();
  for (int d = 128; d > 0; d >>= 1){
    if (threadIdx.x < d) sh[threadIdx.x] += sh[threadIdx.x + d];
    __syncthreads();
  }
  if (threadIdx.x == 0) bsum[blockIdx.x] = sh[0];
}

__global__ __launch_bounds__(256) void scan_bsum(int* __restrict__ bsum, int nb){
  __shared__ int sh[256];
  int tid = threadIdx.x;
  int v = (tid < nb) ? bsum[tid] : 0;
  sh[tid] = v; __syncthreads();
  for (int d = 1; d < 256; d <<= 1){
    int t = (tid >= d) ? sh[tid-d] : 0;
    __syncthreads();
    sh[tid] += t;
    __syncthreads();
  }
  if (tid < nb) bsum[tid] = sh[tid] - v; // exclusive
}

__global__ __launch_bounds__(256) void scan_fill(const int* __restrict__ indeg,
                                                 const int* __restrict__ bsum,
                                                 int* __restrict__ rowstart,
                                                 int* __restrict__ cursor, int N){
  __shared__ int sh[256];
  int base = blockIdx.x * SCAN_CHUNK;
  int tid = threadIdx.x;
  int i0 = base + tid*4;
  int v[4]; int s = 0;
  #pragma unroll
  for (int j=0;j<4;j++){
    int idx = i0 + j;
    v[j] = (idx < N) ? indeg[idx] : 0;
    s += v[j];
  }
  sh[tid] = s; __syncthreads();
  for (int d = 1; d < 256; d <<= 1){
    int t = (tid >= d) ? sh[tid-d] : 0;
    __syncthreads();
    sh[tid] += t;
    __syncthreads();
  }
  int off = bsum[blockIdx.x] + sh[tid] - s;  // exclusive offset for this thread's 4 elems
  #pragma unroll
  for (int j=0;j<4;j++){
    int idx = i0 + j;
    if (idx < N){ rowstart[idx] = off; cursor[idx] = off; }
    off += v[j];
  }
  if (blockIdx.x == gridDim.x - 1 && tid == 255) rowstart[N] = off;
}

__global__ void fill_csr(const int* __restrict__ src, const int* __restrict__ dst,
                         const float* __restrict__ dinv, int* __restrict__ cursor,
                         int* __restrict__ csrs, float* __restrict__ csrn, int E){
  int e = blockIdx.x*blockDim.x + threadIdx.x;
  if (e < E){
    int s = src[e], d = dst[e];
    int pos = atomicAdd(&cursor[d], 1);
    csrs[pos] = s;
    csrn[pos] = dinv[s]*dinv[d];
  }
}

__global__ void gbounds(const int* __restrict__ batch, int* __restrict__ gstart, int N, int G){
  int g = blockIdx.x*blockDim.x + threadIdx.x;
  if (g > G) return;
  int lo = 0, hi = N;
  while (lo < hi){ int mid = (lo+hi)>>1; if (batch[mid] < g) lo = mid+1; else hi = mid; }
  gstart[g] = lo;
}

__global__ void transpose_w(const float* __restrict__ W0, const float* __restrict__ W1,
                            const float* __restrict__ W2, float* __restrict__ Wt){
  int idx = blockIdx.x*blockDim.x + threadIdx.x;
  if (idx >= 3*16384) return;
  int l = idx >> 14, r = idx & 16383, c = r >> 7, k = r & 127;
  const float* W = (l==0) ? W0 : (l==1) ? W1 : W2;
  Wt[idx] = W[k*128 + c];
}

// ---------------- GEMM: C[N,128] = A[N,128] @ W  (Bt = W^T, [col][k]) ----------------
__device__ __forceinline__ int swz64(int i, int k4){
  return i*64 + (((k4 + (i>>3)) & 15) << 2);
}

__global__ __launch_bounds__(256) void gemm128(const float* __restrict__ A, const float* __restrict__ Bt,
                                               float* __restrict__ C, int N){
  __shared__ float As[8192];  // 128 rows x 64 k (swizzled), 32 KB
  __shared__ float Bs[8192];  // 128 cols x 64 k (swizzled), 32 KB
  int tid = threadIdx.x;
  int r0 = blockIdx.x * 128;
  int tx = tid & 15, ty = tid >> 4;
  float acc[8][8];
  #pragma unroll
  for (int r=0;r<8;r++)
    #pragma unroll
    for (int c=0;c<8;c++) acc[r][c] = 0.f;

  for (int st = 0; st < 2; ++st){
    if (st) __syncthreads();
    for (int it = 0; it < 8; ++it){
      int idx = tid + it*256;       // 0..2047
      int i = idx >> 4, k4 = idx & 15;
      int r = r0 + i;
      float4 av = (r < N) ? *(const float4*)(A + (size_t)r*128 + st*64 + k4*4)
                          : make_float4(0.f,0.f,0.f,0.f);
      *(float4*)(As + swz64(i,k4)) = av;
      float4 bv = *(const float4*)(Bt + (size_t)i*128 + st*64 + k4*4);
      *(float4*)(Bs + swz64(i,k4)) = bv;
    }
    __syncthreads();
    for (int k4 = 0; k4 < 16; ++k4){
      float4 a[8], b[8];
      #pragma unroll
      for (int r=0;r<8;r++) a[r] = *(const float4*)(As + swz64(ty*8+r, k4));
      #pragma unroll
      for (int c=0;c<8;c++) b[c] = *(const float4*)(Bs + swz64(tx*8+c, k4));
      #pragma unroll
      for (int r=0;r<8;r++)
        #pragma unroll
        for (int c=0;c<8;c++)
          acc[r][c] += a[r].x*b[c].x + a[r].y*b[c].y + a[r].z*b[c].z + a[r].w*b[c].w;
    }
  }

  #pragma unroll
  for (int r=0;r<8;r++){
    int rr = r0 + ty*8 + r;
    if (rr < N){
      float4 o0 = make_float4(acc[r][0], acc[r][1], acc[r][2], acc[r][3]);
      float4 o1 = make_float4(acc[r][4], acc[r][5], acc[r][6], acc[r][7]);
      *(float4*)(C + (size_t)rr*128 + tx*8)     = o0;
      *(float4*)(C + (size_t)rr*128 + tx*8 + 4) = o1;
    }
  }
}

// ---------------- fused aggregation + bias + squash + attention ----------------
__global__ __launch_bounds__(256) void gather_squash(
    const float* __restrict__ m, const int* __restrict__ rowstart,
    const int* __restrict__ csrs, const float* __restrict__ csrn,
    const float* __restrict__ dinv, const float* __restrict__ bias,
    const float* __restrict__ tar, float* __restrict__ h, float* __restrict__ attn, int N){
  int node = blockIdx.x*4 + (threadIdx.x >> 6);
  if (node >= N) return;
  int lane = threadIdx.x & 63;
  float dv = dinv[node];
  float sn = dv*dv;   // self-loop norm = 1/deg
  float2 v = ((const float2*)(m + (size_t)node*128))[lane];
  float a0 = v.x*sn, a1 = v.y*sn;
  int j0 = rowstart[node], j1 = rowstart[node+1];
  for (int j = j0; j < j1; ++j){
    int s = csrs[j];
    float w = csrn[j];
    float2 mv = ((const float2*)(m + (size_t)s*128))[lane];
    a0 += w*mv.x; a1 += w*mv.y;
  }
  float2 bv = ((const float2*)bias)[lane];
  a0 += bv.x; a1 += bv.y;
  float n2 = a0*a0 + a1*a1;
  #pragma unroll
  for (int o = 32; o > 0; o >>= 1) n2 += __shfl_xor(n2, o);
  float sc = (n2/(1.f+n2)) * rsqrtf(n2 + 1e-12f);
  float h0 = a0*sc, h1 = a1*sc;
  ((float2*)(h + (size_t)node*128))[lane] = make_float2(h0, h1);
  float2 tv = ((const float2*)tar)[lane];
  float at = h0*tv.x + h1*tv.y;
  #pragma unroll
  for (int o = 32; o > 0; o >>= 1) at += __shfl_xor(at, o);
  if (lane == 0) attn[node] = at;
}

// ---------------- per-graph readout (wsum / mean / max), accumulated ----------------
__global__ __launch_bounds__(1024) void readout(const float* __restrict__ h,
                                                const float* __restrict__ attn,
                                                const int* __restrict__ gstart,
                                                float* __restrict__ grep){
  int g = blockIdx.x;
  int t   = threadIdx.x & 127;  // feature
  int grp = threadIdx.x >> 7;   // 0..7 node groups
  int a = gstart[g], b = gstart[g+1];
  float ws = 0.f, sm = 0.f, mx = -INFINITY;
  for (int n = a + grp; n < b; n += 8){
    float v  = h[(size_t)n*128 + t];
    float at = attn[n];
    ws += at*v; sm += v; mx = fmaxf(mx, v);
  }
  __shared__ float sws[8][128], ssm[8][128], smx[8][128];
  sws[grp][t] = ws; ssm[grp][t] = sm; smx[grp][t] = mx;
  __syncthreads();
  if (grp == 0){
    #pragma unroll
    for (int j = 1; j < 8; ++j){
      ws += sws[j][t]; sm += ssm[j][t]; mx = fmaxf(mx, smx[j][t]);
    }
    int cnt = b - a;
    float mean = sm / fmaxf((float)cnt, 1.f);
    if (cnt == 0) mx = 0.f;
    grep[(size_t)g*384 + t]       += ws;
    grep[(size_t)g*384 + 128 + t] += mean;
    grep[(size_t)g*384 + 256 + t] += mx;
  }
}

// ---------------- classifier head + log_softmax ----------------
__global__ __launch_bounds__(128) void classify(const float* __restrict__ grep,
                                                const float* __restrict__ w1, const float* __restrict__ b1,
                                                const float* __restrict__ w2, const float* __restrict__ b2,
                                                float* __restrict__ out){
  int g = blockIdx.x, t = threadIdx.x;
  __shared__ float gr[384];
  for (int i = t; i < 384; i += 128) gr[i] = grep[(size_t)g*384 + i];
  __syncthreads();
  float z = b1[t];
  for (int k = 0; k < 384; ++k) z += gr[k]*w1[k*128 + t];
  z = fmaxf(z, 0.f);
  float c0 = z*w2[t*2 + 0], c1 = z*w2[t*2 + 1];
  #pragma unroll
  for (int o = 32; o > 0; o >>= 1){ c0 += __shfl_xor(c0, o); c1 += __shfl_xor(c1, o); }
  __shared__ float r0s[2], r1s[2];
  if ((t & 63) == 0){ r0s[t>>6] = c0; r1s[t>>6] = c1; }
  __syncthreads();
  if (t == 0){
    float z0 = r0s[0] + r0s[1] + b2[0];
    float z1 = r1s[0] + r1s[1] + b2[1];
    float mm = fmaxf(z0, z1);
    float lse = mm + logf(expf(z0-mm) + expf(z1-mm));
    out[g*2 + 0] = z0 - lse;
    out[g*2 + 1] = z1 - lse;
  }
}

extern "C" void kernel_launch(void* const* d_in, const int* in_sizes, int n_in,
                              void* d_out, int out_size, void* d_ws, size_t ws_size,
                              hipStream_t stream) {
  const float* x     = (const float*)d_in[0];
  const int*   ei    = (const int*)d_in[1];
  const int*   batch = (const int*)d_in[2];
  const float* gamma = (const float*)d_in[3];
  const float* beta  = (const float*)d_in[4];
  const float* W0    = (const float*)d_in[5];
  const float* b0    = (const float*)d_in[6];
  const float* W1    = (const float*)d_in[7];
  const float* b1    = (const float*)d_in[8];
  const float* W2    = (const float*)d_in[9];
  const float* b2    = (const float*)d_in[10];
  const float* tar   = (const float*)d_in[11];
  const float* l1w   = (const float*)d_in[12];
  const float* l1b   = (const float*)d_in[13];
  const float* l2w   = (const float*)d_in[14];
  const float* l2b   = (const float*)d_in[15];
  float* out = (float*)d_out;

  int N = in_sizes[0] / 128;
  int E = in_sizes[1] / 2;
  int G = out_size / 2;
  const int* srcp = ei;
  const int* dstp = ei + E;

  char* wsb = (char*)d_ws;
  size_t off = 0;
  auto alloc = [&](size_t bytes)->char*{
    char* p = wsb + off; off += (bytes + 255) & ~(size_t)255; return p;
  };
  float* h       = (float*)alloc((size_t)N*128*4);
  float* m       = (float*)alloc((size_t)N*128*4);
  float* attn    = (float*)alloc((size_t)N*4);
  float* dinv    = (float*)alloc((size_t)N*4);
  int*   indeg   = (int*)  alloc((size_t)N*4);
  int*   rowst   = (int*)  alloc((size_t)(N+1)*4);
  int*   cursor  = (int*)  alloc((size_t)N*4);
  int*   csrs    = (int*)  alloc((size_t)E*4);
  float* csrn    = (float*)alloc((size_t)E*4);
  int*   gstart  = (int*)  alloc((size_t)(G+1)*4);
  float* grep    = (float*)alloc((size_t)G*384*4);
  float* stats   = (float*)alloc(4*128*4);
  float* Wt      = (float*)alloc(3*16384*4);
  int*   bsum    = (int*)  alloc(256*4);
  (void)ws_size;

  float* colsum = stats;
  float* colsq  = stats + 128;
  float* scale  = stats + 256;
  float* shift  = stats + 384;

  hipMemsetAsync(colsum, 0, 2*128*4, stream);
  hipMemsetAsync(indeg, 0, (size_t)N*4, stream);
  hipMemsetAsync(grep, 0, (size_t)G*384*4, stream);

  bn_stats<<<512, 128, 0, stream>>>(x, colsum, colsq, N);
  bn_finalize<<<1, 128, 0, stream>>>(colsum, colsq, gamma, beta, scale, shift, N);
  bn_apply<<<2048, 256, 0, stream>>>(x, scale, shift, h, N*32);

  int nb = (N + SCAN_CHUNK - 1) / SCAN_CHUNK;   // 98 for N=100000; must be <=256
  count_deg<<<(E+255)/256, 256, 0, stream>>>(dstp, indeg, E);
  dinv_k<<<(N+255)/256, 256, 0, stream>>>(indeg, dinv, N);
  scan_part<<<nb, 256, 0, stream>>>(indeg, bsum, N);
  scan_bsum<<<1, 256, 0, stream>>>(bsum, nb);
  scan_fill<<<nb, 256, 0, stream>>>(indeg, bsum, rowst, cursor, N);
  fill_csr<<<(E+255)/256, 256, 0, stream>>>(srcp, dstp, dinv, cursor, csrs, csrn, E);
  gbounds<<<(G+1+255)/256, 256, 0, stream>>>(batch, gstart, N, G);
  transpose_w<<<(3*16384+255)/256, 256, 0, stream>>>(W0, W1, W2, Wt);

  const float* bs[3] = {b0, b1, b2};
  for (int l = 0; l < 3; ++l){
    gemm128<<<(N+127)/128, 256, 0, stream>>>(h, Wt + l*16384, m, N);
    gather_squash<<<(N+3)/4, 256, 0, stream>>>(m, rowst, csrs, csrn, dinv, bs[l], tar + l*128, h, attn, N);
    readout<<<G, 1024, 0, stream>>>(h, attn, gstart, grep);
  }
  classify<<<G, 128, 0, stream>>>(grep, l1w, l1b, l2w, l2b, out);
}

// Round 3
// 590.269 us; speedup vs baseline: 1.4958x; 1.1337x over previous
//
#include <hip/hip_runtime.h>
#include <hip/hip_bf16.h>
#include <math.h>

#define BN_EPS 1e-5f
#define SCAN_CHUNK 1024

// ---------------- BatchNorm stats: float4 vectorized, LDS reduce ----------------
__global__ __launch_bounds__(256) void bn_stats(const float* __restrict__ x,
                                                float* __restrict__ colsum,
                                                float* __restrict__ colsq, int total4){
  const float4* x4 = (const float4*)x;
  int stride = gridDim.x * blockDim.x;          // multiple of 32 -> c4 fixed per thread
  int idx0 = blockIdx.x * blockDim.x + threadIdx.x;
  float4 s = make_float4(0.f,0.f,0.f,0.f);
  float4 q = make_float4(0.f,0.f,0.f,0.f);
  for (int idx = idx0; idx < total4; idx += stride){
    float4 v = x4[idx];
    s.x += v.x; s.y += v.y; s.z += v.z; s.w += v.w;
    q.x += v.x*v.x; q.y += v.y*v.y; q.z += v.z*v.z; q.w += v.w*v.w;
  }
  __shared__ float4 shs[256], shq[256];
  shs[threadIdx.x] = s; shq[threadIdx.x] = q;
  __syncthreads();
  if (threadIdx.x < 32){
    int c4 = threadIdx.x;
    float4 ts = shs[c4], tq = shq[c4];
    #pragma unroll
    for (int j = 1; j < 8; ++j){
      float4 os = shs[c4 + j*32], oq = shq[c4 + j*32];
      ts.x += os.x; ts.y += os.y; ts.z += os.z; ts.w += os.w;
      tq.x += oq.x; tq.y += oq.y; tq.z += oq.z; tq.w += oq.w;
    }
    atomicAdd(&colsum[c4*4+0], ts.x); atomicAdd(&colsum[c4*4+1], ts.y);
    atomicAdd(&colsum[c4*4+2], ts.z); atomicAdd(&colsum[c4*4+3], ts.w);
    atomicAdd(&colsq[c4*4+0], tq.x);  atomicAdd(&colsq[c4*4+1], tq.y);
    atomicAdd(&colsq[c4*4+2], tq.z);  atomicAdd(&colsq[c4*4+3], tq.w);
  }
}

__global__ void bn_finalize(const float* colsum, const float* colsq, const float* gamma,
                            const float* beta, float* scale, float* shift, int N){
  int c = threadIdx.x;
  float mu  = colsum[c] / (float)N;
  float var = colsq[c] / (float)N - mu*mu;
  float sc  = gamma[c] * rsqrtf(var + BN_EPS);
  scale[c] = sc;
  shift[c] = beta[c] - mu*sc;
}

__global__ void bn_apply(const float* __restrict__ x, const float* __restrict__ scale,
                         const float* __restrict__ shift, float* __restrict__ h, int total4){
  const float4* x4 = (const float4*)x;
  const float4* sc4 = (const float4*)scale;
  const float4* sh4 = (const float4*)shift;
  float4* h4 = (float4*)h;
  for (int idx = blockIdx.x*blockDim.x + threadIdx.x; idx < total4; idx += gridDim.x*blockDim.x){
    int c4 = idx & 31;
    float4 v = x4[idx], sc = sc4[c4], sh = sh4[c4];
    float4 o;
    o.x = v.x*sc.x + sh.x; o.y = v.y*sc.y + sh.y;
    o.z = v.z*sc.z + sh.z; o.w = v.w*sc.w + sh.w;
    h4[idx] = o;
  }
}

// ---------------- CSR build ----------------
__global__ void count_deg(const int* __restrict__ dst, int* __restrict__ indeg, int E){
  int e = blockIdx.x*blockDim.x + threadIdx.x;
  if (e < E) atomicAdd(&indeg[dst[e]], 1);
}

__global__ void dinv_k(const int* __restrict__ indeg, float* __restrict__ dinv, int N){
  int v = blockIdx.x*blockDim.x + threadIdx.x;
  if (v < N) dinv[v] = rsqrtf((float)indeg[v] + 1.0f);  // +1 self loop
}

// ---- hierarchical exclusive scan of indeg -> rowstart, cursor ----
__global__ __launch_bounds__(256) void scan_part(const int* __restrict__ indeg,
                                                 int* __restrict__ bsum, int N){
  __shared__ int sh[256];
  int base = blockIdx.x * SCAN_CHUNK;
  int s = 0;
  for (int i = threadIdx.x; i < SCAN_CHUNK; i += 256){
    int idx = base + i;
    if (idx < N) s += indeg[idx];
  }
  sh[threadIdx.x] = s; __syncthreads();
  for (int d = 128; d > 0; d >>= 1){
    if (threadIdx.x < d) sh[threadIdx.x] += sh[threadIdx.x + d];
    __syncthreads();
  }
  if (threadIdx.x == 0) bsum[blockIdx.x] = sh[0];
}

__global__ __launch_bounds__(256) void scan_bsum(int* __restrict__ bsum, int nb){
  __shared__ int sh[256];
  int tid = threadIdx.x;
  int v = (tid < nb) ? bsum[tid] : 0;
  sh[tid] = v; __syncthreads();
  for (int d = 1; d < 256; d <<= 1){
    int t = (tid >= d) ? sh[tid-d] : 0;
    __syncthreads();
    sh[tid] += t;
    __syncthreads();
  }
  if (tid < nb) bsum[tid] = sh[tid] - v; // exclusive
}

__global__ __launch_bounds__(256) void scan_fill(const int* __restrict__ indeg,
                                                 const int* __restrict__ bsum,
                                                 int* __restrict__ rowstart,
                                                 int* __restrict__ cursor, int N){
  __shared__ int sh[256];
  int base = blockIdx.x * SCAN_CHUNK;
  int tid = threadIdx.x;
  int i0 = base + tid*4;
  int v[4]; int s = 0;
  #pragma unroll
  for (int j=0;j<4;j++){
    int idx = i0 + j;
    v[j] = (idx < N) ? indeg[idx] : 0;
    s += v[j];
  }
  sh[tid] = s; __syncthreads();
  for (int d = 1; d < 256; d <<= 1){
    int t = (tid >= d) ? sh[tid-d] : 0;
    __syncthreads();
    sh[tid] += t;
    __syncthreads();
  }
  int off = bsum[blockIdx.x] + sh[tid] - s;
  #pragma unroll
  for (int j=0;j<4;j++){
    int idx = i0 + j;
    if (idx < N){ rowstart[idx] = off; cursor[idx] = off; }
    off += v[j];
  }
  if (blockIdx.x == gridDim.x - 1 && tid == 255) rowstart[N] = off;
}

__global__ void fill_csr(const int* __restrict__ src, const int* __restrict__ dst,
                         const float* __restrict__ dinv, int* __restrict__ cursor,
                         int* __restrict__ csrs, float* __restrict__ csrn, int E){
  int e = blockIdx.x*blockDim.x + threadIdx.x;
  if (e < E){
    int s = src[e], d = dst[e];
    int pos = atomicAdd(&cursor[d], 1);
    csrs[pos] = s;
    csrn[pos] = dinv[s]*dinv[d];
  }
}

__global__ void gbounds(const int* __restrict__ batch, int* __restrict__ gstart, int N, int G){
  int g = blockIdx.x*blockDim.x + threadIdx.x;
  if (g > G) return;
  int lo = 0, hi = N;
  while (lo < hi){ int mid = (lo+hi)>>1; if (batch[mid] < g) lo = mid+1; else hi = mid; }
  gstart[g] = lo;
}

__global__ void transpose_w(const float* __restrict__ W0, const float* __restrict__ W1,
                            const float* __restrict__ W2, float* __restrict__ Wt){
  int idx = blockIdx.x*blockDim.x + threadIdx.x;
  if (idx >= 3*16384) return;
  int l = idx >> 14, r = idx & 16383, c = r >> 7, k = r & 127;
  const float* W = (l==0) ? W0 : (l==1) ? W1 : W2;
  Wt[idx] = W[k*128 + c];
}

// ---------------- GEMM: C[N,128] = A[N,128] @ W  (Bt = W^T, [col][k]) ----------------
__device__ __forceinline__ int swz64(int i, int k4){
  return i*64 + (((k4 + (i>>3)) & 15) << 2);
}

__global__ __launch_bounds__(256) void gemm128(const float* __restrict__ A, const float* __restrict__ Bt,
                                               float* __restrict__ C, int N){
  __shared__ float As[8192];
  __shared__ float Bs[8192];
  int tid = threadIdx.x;
  int r0 = blockIdx.x * 128;
  int tx = tid & 15, ty = tid >> 4;
  float acc[8][8];
  #pragma unroll
  for (int r=0;r<8;r++)
    #pragma unroll
    for (int c=0;c<8;c++) acc[r][c] = 0.f;

  for (int st = 0; st < 2; ++st){
    if (st) __syncthreads();
    for (int it = 0; it < 8; ++it){
      int idx = tid + it*256;
      int i = idx >> 4, k4 = idx & 15;
      int r = r0 + i;
      float4 av = (r < N) ? *(const float4*)(A + (size_t)r*128 + st*64 + k4*4)
                          : make_float4(0.f,0.f,0.f,0.f);
      *(float4*)(As + swz64(i,k4)) = av;
      float4 bv = *(const float4*)(Bt + (size_t)i*128 + st*64 + k4*4);
      *(float4*)(Bs + swz64(i,k4)) = bv;
    }
    __syncthreads();
    for (int k4 = 0; k4 < 16; ++k4){
      float4 a[8], b[8];
      #pragma unroll
      for (int r=0;r<8;r++) a[r] = *(const float4*)(As + swz64(ty*8+r, k4));
      #pragma unroll
      for (int c=0;c<8;c++) b[c] = *(const float4*)(Bs + swz64(tx*8+c, k4));
      #pragma unroll
      for (int r=0;r<8;r++)
        #pragma unroll
        for (int c=0;c<8;c++)
          acc[r][c] += a[r].x*b[c].x + a[r].y*b[c].y + a[r].z*b[c].z + a[r].w*b[c].w;
    }
  }

  #pragma unroll
  for (int r=0;r<8;r++){
    int rr = r0 + ty*8 + r;
    if (rr < N){
      float4 o0 = make_float4(acc[r][0], acc[r][1], acc[r][2], acc[r][3]);
      float4 o1 = make_float4(acc[r][4], acc[r][5], acc[r][6], acc[r][7]);
      *(float4*)(C + (size_t)rr*128 + tx*8)     = o0;
      *(float4*)(C + (size_t)rr*128 + tx*8 + 4) = o1;
    }
  }
}

// ---------------- fused aggregation + bias + squash + attention ----------------
// One wave per node. Edge indices/weights preloaded coalesced into lanes,
// broadcast via shuffle; gathers unrolled x4 for memory-level parallelism.
__global__ __launch_bounds__(256) void gather_squash(
    const float* __restrict__ m, const int* __restrict__ rowstart,
    const int* __restrict__ csrs, const float* __restrict__ csrn,
    const float* __restrict__ dinv, const float* __restrict__ bias,
    const float* __restrict__ tar, float* __restrict__ h, float* __restrict__ attn, int N){
  int node = blockIdx.x*4 + (threadIdx.x >> 6);
  if (node >= N) return;
  int lane = threadIdx.x & 63;
  float dv = dinv[node];
  float sn = dv*dv;   // self-loop norm = 1/deg
  float2 v = ((const float2*)(m + (size_t)node*128))[lane];
  float a0 = v.x*sn, a1 = v.y*sn;
  int j0 = rowstart[node], j1 = rowstart[node+1];

  for (int base = j0; base < j1; base += 64){
    int cnt = j1 - base; if (cnt > 64) cnt = 64;
    int   sidx = 0; float swt = 0.f;
    if (lane < cnt){ sidx = csrs[base + lane]; swt = csrn[base + lane]; }
    int t = 0;
    for (; t + 4 <= cnt; t += 4){
      int s0 = __shfl(sidx, t),   s1 = __shfl(sidx, t+1);
      int s2 = __shfl(sidx, t+2), s3 = __shfl(sidx, t+3);
      float w0 = __shfl(swt, t),   w1 = __shfl(swt, t+1);
      float w2 = __shfl(swt, t+2), w3 = __shfl(swt, t+3);
      float2 m0 = ((const float2*)(m + (size_t)s0*128))[lane];
      float2 m1 = ((const float2*)(m + (size_t)s1*128))[lane];
      float2 m2 = ((const float2*)(m + (size_t)s2*128))[lane];
      float2 m3 = ((const float2*)(m + (size_t)s3*128))[lane];
      a0 += w0*m0.x + w1*m1.x + w2*m2.x + w3*m3.x;
      a1 += w0*m0.y + w1*m1.y + w2*m2.y + w3*m3.y;
    }
    for (; t < cnt; ++t){
      int s = __shfl(sidx, t);
      float w = __shfl(swt, t);
      float2 mv = ((const float2*)(m + (size_t)s*128))[lane];
      a0 += w*mv.x; a1 += w*mv.y;
    }
  }

  float2 bv = ((const float2*)bias)[lane];
  a0 += bv.x; a1 += bv.y;
  float n2 = a0*a0 + a1*a1;
  #pragma unroll
  for (int o = 32; o > 0; o >>= 1) n2 += __shfl_xor(n2, o);
  float sc = (n2/(1.f+n2)) * rsqrtf(n2 + 1e-12f);
  float h0 = a0*sc, h1 = a1*sc;
  ((float2*)(h + (size_t)node*128))[lane] = make_float2(h0, h1);
  float2 tv = ((const float2*)tar)[lane];
  float at = h0*tv.x + h1*tv.y;
  #pragma unroll
  for (int o = 32; o > 0; o >>= 1) at += __shfl_xor(at, o);
  if (lane == 0) attn[node] = at;
}

// ---------------- per-graph readout (wsum / mean / max), accumulated ----------------
__global__ __launch_bounds__(1024) void readout(const float* __restrict__ h,
                                                const float* __restrict__ attn,
                                                const int* __restrict__ gstart,
                                                float* __restrict__ grep){
  int g = blockIdx.x;
  int t   = threadIdx.x & 127;
  int grp = threadIdx.x >> 7;
  int a = gstart[g], b = gstart[g+1];
  float ws = 0.f, sm = 0.f, mx = -INFINITY;
  for (int n = a + grp; n < b; n += 8){
    float v  = h[(size_t)n*128 + t];
    float at = attn[n];
    ws += at*v; sm += v; mx = fmaxf(mx, v);
  }
  __shared__ float sws[8][128], ssm[8][128], smx[8][128];
  sws[grp][t] = ws; ssm[grp][t] = sm; smx[grp][t] = mx;
  __syncthreads();
  if (grp == 0){
    #pragma unroll
    for (int j = 1; j < 8; ++j){
      ws += sws[j][t]; sm += ssm[j][t]; mx = fmaxf(mx, smx[j][t]);
    }
    int cnt = b - a;
    float mean = sm / fmaxf((float)cnt, 1.f);
    if (cnt == 0) mx = 0.f;
    grep[(size_t)g*384 + t]       += ws;
    grep[(size_t)g*384 + 128 + t] += mean;
    grep[(size_t)g*384 + 256 + t] += mx;
  }
}

// ---------------- classifier head + log_softmax ----------------
__global__ __launch_bounds__(128) void classify(const float* __restrict__ grep,
                                                const float* __restrict__ w1, const float* __restrict__ b1,
                                                const float* __restrict__ w2, const float* __restrict__ b2,
                                                float* __restrict__ out){
  int g = blockIdx.x, t = threadIdx.x;
  __shared__ float gr[384];
  for (int i = t; i < 384; i += 128) gr[i] = grep[(size_t)g*384 + i];
  __syncthreads();
  float z = b1[t];
  for (int k = 0; k < 384; ++k) z += gr[k]*w1[k*128 + t];
  z = fmaxf(z, 0.f);
  float c0 = z*w2[t*2 + 0], c1 = z*w2[t*2 + 1];
  #pragma unroll
  for (int o = 32; o > 0; o >>= 1){ c0 += __shfl_xor(c0, o); c1 += __shfl_xor(c1, o); }
  __shared__ float r0s[2], r1s[2];
  if ((t & 63) == 0){ r0s[t>>6] = c0; r1s[t>>6] = c1; }
  __syncthreads();
  if (t == 0){
    float z0 = r0s[0] + r0s[1] + b2[0];
    float z1 = r1s[0] + r1s[1] + b2[1];
    float mm = fmaxf(z0, z1);
    float lse = mm + logf(expf(z0-mm) + expf(z1-mm));
    out[g*2 + 0] = z0 - lse;
    out[g*2 + 1] = z1 - lse;
  }
}

extern "C" void kernel_launch(void* const* d_in, const int* in_sizes, int n_in,
                              void* d_out, int out_size, void* d_ws, size_t ws_size,
                              hipStream_t stream) {
  const float* x     = (const float*)d_in[0];
  const int*   ei    = (const int*)d_in[1];
  const int*   batch = (const int*)d_in[2];
  const float* gamma = (const float*)d_in[3];
  const float* beta  = (const float*)d_in[4];
  const float* W0    = (const float*)d_in[5];
  const float* b0    = (const float*)d_in[6];
  const float* W1    = (const float*)d_in[7];
  const float* b1    = (const float*)d_in[8];
  const float* W2    = (const float*)d_in[9];
  const float* b2    = (const float*)d_in[10];
  const float* tar   = (const float*)d_in[11];
  const float* l1w   = (const float*)d_in[12];
  const float* l1b   = (const float*)d_in[13];
  const float* l2w   = (const float*)d_in[14];
  const float* l2b   = (const float*)d_in[15];
  float* out = (float*)d_out;

  int N = in_sizes[0] / 128;
  int E = in_sizes[1] / 2;
  int G = out_size / 2;
  const int* srcp = ei;
  const int* dstp = ei + E;

  char* wsb = (char*)d_ws;
  size_t off = 0;
  auto alloc = [&](size_t bytes)->char*{
    char* p = wsb + off; off += (bytes + 255) & ~(size_t)255; return p;
  };
  float* h       = (float*)alloc((size_t)N*128*4);
  float* m       = (float*)alloc((size_t)N*128*4);
  float* attn    = (float*)alloc((size_t)N*4);
  float* dinv    = (float*)alloc((size_t)N*4);
  int*   indeg   = (int*)  alloc((size_t)N*4);
  int*   rowst   = (int*)  alloc((size_t)(N+1)*4);
  int*   cursor  = (int*)  alloc((size_t)N*4);
  int*   csrs    = (int*)  alloc((size_t)E*4);
  float* csrn    = (float*)alloc((size_t)E*4);
  int*   gstart  = (int*)  alloc((size_t)(G+1)*4);
  float* grep    = (float*)alloc((size_t)G*384*4);
  float* stats   = (float*)alloc(4*128*4);
  float* Wt      = (float*)alloc(3*16384*4);
  int*   bsum    = (int*)  alloc(256*4);
  (void)ws_size;

  float* colsum = stats;
  float* colsq  = stats + 128;
  float* scale  = stats + 256;
  float* shift  = stats + 384;

  hipMemsetAsync(colsum, 0, 2*128*4, stream);
  hipMemsetAsync(indeg, 0, (size_t)N*4, stream);
  hipMemsetAsync(grep, 0, (size_t)G*384*4, stream);

  bn_stats<<<512, 256, 0, stream>>>(x, colsum, colsq, N*32);
  bn_finalize<<<1, 128, 0, stream>>>(colsum, colsq, gamma, beta, scale, shift, N);
  bn_apply<<<2048, 256, 0, stream>>>(x, scale, shift, h, N*32);

  int nb = (N + SCAN_CHUNK - 1) / SCAN_CHUNK;
  count_deg<<<(E+255)/256, 256, 0, stream>>>(dstp, indeg, E);
  dinv_k<<<(N+255)/256, 256, 0, stream>>>(indeg, dinv, N);
  scan_part<<<nb, 256, 0, stream>>>(indeg, bsum, N);
  scan_bsum<<<1, 256, 0, stream>>>(bsum, nb);
  scan_fill<<<nb, 256, 0, stream>>>(indeg, bsum, rowst, cursor, N);
  fill_csr<<<(E+255)/256, 256, 0, stream>>>(srcp, dstp, dinv, cursor, csrs, csrn, E);
  gbounds<<<(G+1+255)/256, 256, 0, stream>>>(batch, gstart, N, G);
  transpose_w<<<(3*16384+255)/256, 256, 0, stream>>>(W0, W1, W2, Wt);

  const float* bs[3] = {b0, b1, b2};
  for (int l = 0; l < 3; ++l){
    gemm128<<<(N+127)/128, 256, 0, stream>>>(h, Wt + l*16384, m, N);
    gather_squash<<<(N+3)/4, 256, 0, stream>>>(m, rowst, csrs, csrn, dinv, bs[l], tar + l*128, h, attn, N);
    readout<<<G, 1024, 0, stream>>>(h, attn, gstart, grep);
  }
  classify<<<G, 128, 0, stream>>>(grep, l1w, l1b, l2w, l2b, out);
}

// Round 4
// 492.575 us; speedup vs baseline: 1.7924x; 1.1983x over previous
//
#include <hip/hip_runtime.h>
#include <hip/hip_bf16.h>
#include <math.h>

#define BN_EPS 1e-5f
#define SCAN_CHUNK 1024

typedef __attribute__((ext_vector_type(8)))  short short8v;
typedef __attribute__((ext_vector_type(16))) float f32x16;

__device__ __forceinline__ unsigned short f2bf(float f){
  union { float f; unsigned u; } v; v.f = f;
  unsigned r = v.u + 0x7FFFu + ((v.u >> 16) & 1u);
  return (unsigned short)(r >> 16);
}
__device__ __forceinline__ float bf2f(unsigned short b){
  union { unsigned u; float f; } v; v.u = ((unsigned)b) << 16;
  return v.f;
}

// ---------------- BatchNorm stats: float4 vectorized, LDS reduce ----------------
__global__ __launch_bounds__(256) void bn_stats(const float* __restrict__ x,
                                                float* __restrict__ colsum,
                                                float* __restrict__ colsq, int total4){
  const float4* x4 = (const float4*)x;
  int stride = gridDim.x * blockDim.x;
  int idx0 = blockIdx.x * blockDim.x + threadIdx.x;
  float4 s = make_float4(0.f,0.f,0.f,0.f);
  float4 q = make_float4(0.f,0.f,0.f,0.f);
  for (int idx = idx0; idx < total4; idx += stride){
    float4 v = x4[idx];
    s.x += v.x; s.y += v.y; s.z += v.z; s.w += v.w;
    q.x += v.x*v.x; q.y += v.y*v.y; q.z += v.z*v.z; q.w += v.w*v.w;
  }
  __shared__ float4 shs[256], shq[256];
  shs[threadIdx.x] = s; shq[threadIdx.x] = q;
  __syncthreads();
  if (threadIdx.x < 32){
    int c4 = threadIdx.x;
    float4 ts = shs[c4], tq = shq[c4];
    #pragma unroll
    for (int j = 1; j < 8; ++j){
      float4 os = shs[c4 + j*32], oq = shq[c4 + j*32];
      ts.x += os.x; ts.y += os.y; ts.z += os.z; ts.w += os.w;
      tq.x += oq.x; tq.y += oq.y; tq.z += oq.z; tq.w += oq.w;
    }
    atomicAdd(&colsum[c4*4+0], ts.x); atomicAdd(&colsum[c4*4+1], ts.y);
    atomicAdd(&colsum[c4*4+2], ts.z); atomicAdd(&colsum[c4*4+3], ts.w);
    atomicAdd(&colsq[c4*4+0], tq.x);  atomicAdd(&colsq[c4*4+1], tq.y);
    atomicAdd(&colsq[c4*4+2], tq.z);  atomicAdd(&colsq[c4*4+3], tq.w);
  }
}

__global__ void bn_finalize(const float* colsum, const float* colsq, const float* gamma,
                            const float* beta, float* scale, float* shift, int N){
  int c = threadIdx.x;
  float mu  = colsum[c] / (float)N;
  float var = colsq[c] / (float)N - mu*mu;
  float sc  = gamma[c] * rsqrtf(var + BN_EPS);
  scale[c] = sc;
  shift[c] = beta[c] - mu*sc;
}

// ---------------- CSR build ----------------
__global__ void count_deg(const int* __restrict__ dst, int* __restrict__ indeg, int E){
  int e = blockIdx.x*blockDim.x + threadIdx.x;
  if (e < E) atomicAdd(&indeg[dst[e]], 1);
}

__global__ void dinv_k(const int* __restrict__ indeg, float* __restrict__ dinv, int N){
  int v = blockIdx.x*blockDim.x + threadIdx.x;
  if (v < N) dinv[v] = rsqrtf((float)indeg[v] + 1.0f);
}

__global__ __launch_bounds__(256) void scan_part(const int* __restrict__ indeg,
                                                 int* __restrict__ bsum, int N){
  __shared__ int sh[256];
  int base = blockIdx.x * SCAN_CHUNK;
  int s = 0;
  for (int i = threadIdx.x; i < SCAN_CHUNK; i += 256){
    int idx = base + i;
    if (idx < N) s += indeg[idx];
  }
  sh[threadIdx.x] = s; __syncthreads();
  for (int d = 128; d > 0; d >>= 1){
    if (threadIdx.x < d) sh[threadIdx.x] += sh[threadIdx.x + d];
    __syncthreads();
  }
  if (threadIdx.x == 0) bsum[blockIdx.x] = sh[0];
}

__global__ __launch_bounds__(256) void scan_bsum(int* __restrict__ bsum, int nb){
  __shared__ int sh[256];
  int tid = threadIdx.x;
  int v = (tid < nb) ? bsum[tid] : 0;
  sh[tid] = v; __syncthreads();
  for (int d = 1; d < 256; d <<= 1){
    int t = (tid >= d) ? sh[tid-d] : 0;
    __syncthreads();
    sh[tid] += t;
    __syncthreads();
  }
  if (tid < nb) bsum[tid] = sh[tid] - v;
}

__global__ __launch_bounds__(256) void scan_fill(const int* __restrict__ indeg,
                                                 const int* __restrict__ bsum,
                                                 int* __restrict__ rowstart,
                                                 int* __restrict__ cursor, int N){
  __shared__ int sh[256];
  int base = blockIdx.x * SCAN_CHUNK;
  int tid = threadIdx.x;
  int i0 = base + tid*4;
  int v[4]; int s = 0;
  #pragma unroll
  for (int j=0;j<4;j++){
    int idx = i0 + j;
    v[j] = (idx < N) ? indeg[idx] : 0;
    s += v[j];
  }
  sh[tid] = s; __syncthreads();
  for (int d = 1; d < 256; d <<= 1){
    int t = (tid >= d) ? sh[tid-d] : 0;
    __syncthreads();
    sh[tid] += t;
    __syncthreads();
  }
  int off = bsum[blockIdx.x] + sh[tid] - s;
  #pragma unroll
  for (int j=0;j<4;j++){
    int idx = i0 + j;
    if (idx < N){ rowstart[idx] = off; cursor[idx] = off; }
    off += v[j];
  }
  if (blockIdx.x == gridDim.x - 1 && tid == 255) rowstart[N] = off;
}

__global__ void fill_csr(const int* __restrict__ src, const int* __restrict__ dst,
                         const float* __restrict__ dinv, int* __restrict__ cursor,
                         int* __restrict__ csrs, float* __restrict__ csrn, int E){
  int e = blockIdx.x*blockDim.x + threadIdx.x;
  if (e < E){
    int s = src[e], d = dst[e];
    int pos = atomicAdd(&cursor[d], 1);
    csrs[pos] = s;
    csrn[pos] = dinv[s]*dinv[d];
  }
}

__global__ void gbounds(const int* __restrict__ batch, int* __restrict__ gstart, int N, int G){
  int g = blockIdx.x*blockDim.x + threadIdx.x;
  if (g > G) return;
  int lo = 0, hi = N;
  while (lo < hi){ int mid = (lo+hi)>>1; if (batch[mid] < g) lo = mid+1; else hi = mid; }
  gstart[g] = lo;
}

// ---- split W into bf16 hi/lo, transposed layout Wt[l][c][k] ----
__global__ void prep_w(const float* __restrict__ W0, const float* __restrict__ W1,
                       const float* __restrict__ W2, unsigned short* __restrict__ Wh,
                       unsigned short* __restrict__ Wl){
  int idx = blockIdx.x*blockDim.x + threadIdx.x;
  if (idx >= 3*16384) return;
  int l = idx >> 14, r = idx & 16383, c = r >> 7, k = r & 127;
  const float* W = (l==0) ? W0 : (l==1) ? W1 : W2;
  float v = W[k*128 + c];
  unsigned short h = f2bf(v);
  Wh[idx] = h;
  Wl[idx] = f2bf(v - bf2f(h));
}

// ---------------- split-bf16 MFMA GEMM: C[N,128] = A[N,128] @ W ----------------
// Block: 256 thr = 4 waves, 64 rows x 128 cols.
// Wave w: rows 32*(w&1)..+31, col tiles (w>>1)*64 and (w>>1)*64+32.
// A staged in LDS as bf16 hi/lo, XOR-swizzled (byte ^ (row&15)<<4).
// Optional fused BatchNorm (scale/shift) on the A load.
__global__ __launch_bounds__(256) void gemm_mfma(
    const float* __restrict__ A, const unsigned short* __restrict__ Bh,
    const unsigned short* __restrict__ Bl, const float* __restrict__ scale,
    const float* __restrict__ shift, float* __restrict__ C, int N){
  __shared__ unsigned short Ah[64*128];
  __shared__ unsigned short Al[64*128];
  int tid = threadIdx.x;
  int r0 = blockIdx.x * 64;

  // ---- stage A (fp32 -> bf16 hi/lo into LDS) ----
  #pragma unroll
  for (int it = 0; it < 8; ++it){
    int idx = tid + it*256;          // 0..2047 float4s
    int row = idx >> 5;              // 0..63
    int c4  = idx & 31;              // float4 column
    int r = r0 + row;
    float4 av = (r < N) ? *(const float4*)(A + (size_t)r*128 + c4*4)
                        : make_float4(0.f,0.f,0.f,0.f);
    if (scale){
      float4 sc = *(const float4*)(scale + c4*4);
      float4 sh = *(const float4*)(shift + c4*4);
      av.x = av.x*sc.x + sh.x; av.y = av.y*sc.y + sh.y;
      av.z = av.z*sc.z + sh.z; av.w = av.w*sc.w + sh.w;
    }
    float a[4] = {av.x, av.y, av.z, av.w};
    unsigned short hh[4], ll[4];
    #pragma unroll
    for (int j = 0; j < 4; ++j){
      hh[j] = f2bf(a[j]);
      ll[j] = f2bf(a[j] - bf2f(hh[j]));
    }
    int byte0 = (c4*8) ^ ((row & 15) << 4);
    union { unsigned short u[4]; uint2 v; } ph, pl;
    ph.u[0]=hh[0]; ph.u[1]=hh[1]; ph.u[2]=hh[2]; ph.u[3]=hh[3];
    pl.u[0]=ll[0]; pl.u[1]=ll[1]; pl.u[2]=ll[2]; pl.u[3]=ll[3];
    *(uint2*)((char*)Ah + row*256 + byte0) = ph.v;
    *(uint2*)((char*)Al + row*256 + byte0) = pl.v;
  }
  __syncthreads();

  // ---- MFMA main loop ----
  int w = tid >> 6, lane = tid & 63;
  int rt = w & 1;
  int ct = (w >> 1) * 64;
  int lrow = 32*rt + (lane & 31);
  int khalf = lane >> 5;
  int c0 = ct + (lane & 31);

  f32x16 acc0 = {}, acc1 = {};
  const char* AhB = (const char*)Ah + lrow*256;
  const char* AlB = (const char*)Al + lrow*256;
  const unsigned short* bh0 = Bh + (size_t)c0*128 + khalf*8;
  const unsigned short* bl0 = Bl + (size_t)c0*128 + khalf*8;
  int sw = (lrow & 15) << 4;

  #pragma unroll
  for (int s = 0; s < 8; ++s){
    int abyte = (s*32 + khalf*16) ^ sw;
    short8v a_hi = *(const short8v*)(AhB + abyte);
    short8v a_lo = *(const short8v*)(AlB + abyte);
    short8v b_h0 = *(const short8v*)(bh0 + s*16);
    short8v b_l0 = *(const short8v*)(bl0 + s*16);
    short8v b_h1 = *(const short8v*)(bh0 + 32*128 + s*16);
    short8v b_l1 = *(const short8v*)(bl0 + 32*128 + s*16);
    acc0 = __builtin_amdgcn_mfma_f32_32x32x16_bf16(a_hi, b_h0, acc0, 0, 0, 0);
    acc1 = __builtin_amdgcn_mfma_f32_32x32x16_bf16(a_hi, b_h1, acc1, 0, 0, 0);
    acc0 = __builtin_amdgcn_mfma_f32_32x32x16_bf16(a_hi, b_l0, acc0, 0, 0, 0);
    acc1 = __builtin_amdgcn_mfma_f32_32x32x16_bf16(a_hi, b_l1, acc1, 0, 0, 0);
    acc0 = __builtin_amdgcn_mfma_f32_32x32x16_bf16(a_lo, b_h0, acc0, 0, 0, 0);
    acc1 = __builtin_amdgcn_mfma_f32_32x32x16_bf16(a_lo, b_h1, acc1, 0, 0, 0);
  }

  // ---- epilogue: C/D layout col=lane&31, row=(reg&3)+8*(reg>>2)+4*(lane>>5) ----
  #pragma unroll
  for (int r = 0; r < 16; ++r){
    int row = r0 + 32*rt + (r & 3) + 8*(r >> 2) + 4*khalf;
    if (row < N){
      C[(size_t)row*128 + c0]      = acc0[r];
      C[(size_t)row*128 + c0 + 32] = acc1[r];
    }
  }
}

// ---------------- fused aggregation + bias + squash + attention ----------------
__global__ __launch_bounds__(256) void gather_squash(
    const float* __restrict__ m, const int* __restrict__ rowstart,
    const int* __restrict__ csrs, const float* __restrict__ csrn,
    const float* __restrict__ dinv, const float* __restrict__ bias,
    const float* __restrict__ tar, float* __restrict__ h, float* __restrict__ attn, int N){
  int node = blockIdx.x*4 + (threadIdx.x >> 6);
  if (node >= N) return;
  int lane = threadIdx.x & 63;
  float dv = dinv[node];
  float sn = dv*dv;
  float2 v = ((const float2*)(m + (size_t)node*128))[lane];
  float a0 = v.x*sn, a1 = v.y*sn;
  int j0 = rowstart[node], j1 = rowstart[node+1];

  for (int base = j0; base < j1; base += 64){
    int cnt = j1 - base; if (cnt > 64) cnt = 64;
    int   sidx = 0; float swt = 0.f;
    if (lane < cnt){ sidx = csrs[base + lane]; swt = csrn[base + lane]; }
    int t = 0;
    for (; t + 4 <= cnt; t += 4){
      int s0 = __shfl(sidx, t),   s1 = __shfl(sidx, t+1);
      int s2 = __shfl(sidx, t+2), s3 = __shfl(sidx, t+3);
      float w0 = __shfl(swt, t),   w1 = __shfl(swt, t+1);
      float w2 = __shfl(swt, t+2), w3 = __shfl(swt, t+3);
      float2 m0 = ((const float2*)(m + (size_t)s0*128))[lane];
      float2 m1 = ((const float2*)(m + (size_t)s1*128))[lane];
      float2 m2 = ((const float2*)(m + (size_t)s2*128))[lane];
      float2 m3 = ((const float2*)(m + (size_t)s3*128))[lane];
      a0 += w0*m0.x + w1*m1.x + w2*m2.x + w3*m3.x;
      a1 += w0*m0.y + w1*m1.y + w2*m2.y + w3*m3.y;
    }
    for (; t < cnt; ++t){
      int s = __shfl(sidx, t);
      float w = __shfl(swt, t);
      float2 mv = ((const float2*)(m + (size_t)s*128))[lane];
      a0 += w*mv.x; a1 += w*mv.y;
    }
  }

  float2 bv = ((const float2*)bias)[lane];
  a0 += bv.x; a1 += bv.y;
  float n2 = a0*a0 + a1*a1;
  #pragma unroll
  for (int o = 32; o > 0; o >>= 1) n2 += __shfl_xor(n2, o);
  float sc = (n2/(1.f+n2)) * rsqrtf(n2 + 1e-12f);
  float h0 = a0*sc, h1 = a1*sc;
  ((float2*)(h + (size_t)node*128))[lane] = make_float2(h0, h1);
  float2 tv = ((const float2*)tar)[lane];
  float at = h0*tv.x + h1*tv.y;
  #pragma unroll
  for (int o = 32; o > 0; o >>= 1) at += __shfl_xor(at, o);
  if (lane == 0) attn[node] = at;
}

// ---------------- per-graph readout (wsum / mean / max), accumulated ----------------
__global__ __launch_bounds__(1024) void readout(const float* __restrict__ h,
                                                const float* __restrict__ attn,
                                                const int* __restrict__ gstart,
                                                float* __restrict__ grep){
  int g = blockIdx.x;
  int t   = threadIdx.x & 127;
  int grp = threadIdx.x >> 7;
  int a = gstart[g], b = gstart[g+1];
  float ws = 0.f, sm = 0.f, mx = -INFINITY;
  for (int n = a + grp; n < b; n += 8){
    float v  = h[(size_t)n*128 + t];
    float at = attn[n];
    ws += at*v; sm += v; mx = fmaxf(mx, v);
  }
  __shared__ float sws[8][128], ssm[8][128], smx[8][128];
  sws[grp][t] = ws; ssm[grp][t] = sm; smx[grp][t] = mx;
  __syncthreads();
  if (grp == 0){
    #pragma unroll
    for (int j = 1; j < 8; ++j){
      ws += sws[j][t]; sm += ssm[j][t]; mx = fmaxf(mx, smx[j][t]);
    }
    int cnt = b - a;
    float mean = sm / fmaxf((float)cnt, 1.f);
    if (cnt == 0) mx = 0.f;
    grep[(size_t)g*384 + t]       += ws;
    grep[(size_t)g*384 + 128 + t] += mean;
    grep[(size_t)g*384 + 256 + t] += mx;
  }
}

// ---------------- classifier head + log_softmax ----------------
__global__ __launch_bounds__(128) void classify(const float* __restrict__ grep,
                                                const float* __restrict__ w1, const float* __restrict__ b1,
                                                const float* __restrict__ w2, const float* __restrict__ b2,
                                                float* __restrict__ out){
  int g = blockIdx.x, t = threadIdx.x;
  __shared__ float gr[384];
  for (int i = t; i < 384; i += 128) gr[i] = grep[(size_t)g*384 + i];
  __syncthreads();
  float z = b1[t];
  for (int k = 0; k < 384; ++k) z += gr[k]*w1[k*128 + t];
  z = fmaxf(z, 0.f);
  float c0 = z*w2[t*2 + 0], c1 = z*w2[t*2 + 1];
  #pragma unroll
  for (int o = 32; o > 0; o >>= 1){ c0 += __shfl_xor(c0, o); c1 += __shfl_xor(c1, o); }
  __shared__ float r0s[2], r1s[2];
  if ((t & 63) == 0){ r0s[t>>6] = c0; r1s[t>>6] = c1; }
  __syncthreads();
  if (t == 0){
    float z0 = r0s[0] + r0s[1] + b2[0];
    float z1 = r1s[0] + r1s[1] + b2[1];
    float mm = fmaxf(z0, z1);
    float lse = mm + logf(expf(z0-mm) + expf(z1-mm));
    out[g*2 + 0] = z0 - lse;
    out[g*2 + 1] = z1 - lse;
  }
}

extern "C" void kernel_launch(void* const* d_in, const int* in_sizes, int n_in,
                              void* d_out, int out_size, void* d_ws, size_t ws_size,
                              hipStream_t stream) {
  const float* x     = (const float*)d_in[0];
  const int*   ei    = (const int*)d_in[1];
  const int*   batch = (const int*)d_in[2];
  const float* gamma = (const float*)d_in[3];
  const float* beta  = (const float*)d_in[4];
  const float* W0    = (const float*)d_in[5];
  const float* b0    = (const float*)d_in[6];
  const float* W1    = (const float*)d_in[7];
  const float* b1    = (const float*)d_in[8];
  const float* W2    = (const float*)d_in[9];
  const float* b2    = (const float*)d_in[10];
  const float* tar   = (const float*)d_in[11];
  const float* l1w   = (const float*)d_in[12];
  const float* l1b   = (const float*)d_in[13];
  const float* l2w   = (const float*)d_in[14];
  const float* l2b   = (const float*)d_in[15];
  float* out = (float*)d_out;

  int N = in_sizes[0] / 128;
  int E = in_sizes[1] / 2;
  int G = out_size / 2;
  const int* srcp = ei;
  const int* dstp = ei + E;

  char* wsb = (char*)d_ws;
  size_t off = 0;
  auto alloc = [&](size_t bytes)->char*{
    char* p = wsb + off; off += (bytes + 255) & ~(size_t)255; return p;
  };
  float* h       = (float*)alloc((size_t)N*128*4);
  float* m       = (float*)alloc((size_t)N*128*4);
  float* attn    = (float*)alloc((size_t)N*4);
  float* dinv    = (float*)alloc((size_t)N*4);
  int*   indeg   = (int*)  alloc((size_t)N*4);
  int*   rowst   = (int*)  alloc((size_t)(N+1)*4);
  int*   cursor  = (int*)  alloc((size_t)N*4);
  int*   csrs    = (int*)  alloc((size_t)E*4);
  float* csrn    = (float*)alloc((size_t)E*4);
  int*   gstart  = (int*)  alloc((size_t)(G+1)*4);
  float* grep    = (float*)alloc((size_t)G*384*4);
  float* stats   = (float*)alloc(4*128*4);
  unsigned short* Wh = (unsigned short*)alloc(3*16384*2);
  unsigned short* Wl = (unsigned short*)alloc(3*16384*2);
  int*   bsum    = (int*)  alloc(256*4);
  (void)ws_size;

  float* colsum = stats;
  float* colsq  = stats + 128;
  float* scale  = stats + 256;
  float* shift  = stats + 384;

  hipMemsetAsync(colsum, 0, 2*128*4, stream);
  hipMemsetAsync(indeg, 0, (size_t)N*4, stream);
  hipMemsetAsync(grep, 0, (size_t)G*384*4, stream);

  bn_stats<<<512, 256, 0, stream>>>(x, colsum, colsq, N*32);
  bn_finalize<<<1, 128, 0, stream>>>(colsum, colsq, gamma, beta, scale, shift, N);

  int nb = (N + SCAN_CHUNK - 1) / SCAN_CHUNK;
  count_deg<<<(E+255)/256, 256, 0, stream>>>(dstp, indeg, E);
  dinv_k<<<(N+255)/256, 256, 0, stream>>>(indeg, dinv, N);
  scan_part<<<nb, 256, 0, stream>>>(indeg, bsum, N);
  scan_bsum<<<1, 256, 0, stream>>>(bsum, nb);
  scan_fill<<<nb, 256, 0, stream>>>(indeg, bsum, rowst, cursor, N);
  fill_csr<<<(E+255)/256, 256, 0, stream>>>(srcp, dstp, dinv, cursor, csrs, csrn, E);
  gbounds<<<(G+1+255)/256, 256, 0, stream>>>(batch, gstart, N, G);
  prep_w<<<(3*16384+255)/256, 256, 0, stream>>>(W0, W1, W2, Wh, Wl);

  const float* bs[3] = {b0, b1, b2};
  for (int l = 0; l < 3; ++l){
    const float* src_mat = (l == 0) ? x : h;
    const float* sc = (l == 0) ? scale : nullptr;
    const float* sh = (l == 0) ? shift : nullptr;
    gemm_mfma<<<(N+63)/64, 256, 0, stream>>>(src_mat, Wh + l*16384, Wl + l*16384, sc, sh, m, N);
    gather_squash<<<(N+3)/4, 256, 0, stream>>>(m, rowst, csrs, csrn, dinv, bs[l], tar + l*128, h, attn, N);
    readout<<<G, 1024, 0, stream>>>(h, attn, gstart, grep);
  }
  classify<<<G, 128, 0, stream>>>(grep, l1w, l1b, l2w, l2b, out);
}